// Round 1
// 1423.552 us; speedup vs baseline: 1.3701x; 1.3701x over previous
//
#include <hip/hip_runtime.h>
#include <cstddef>

// Problem constants
#define Bn 8
#define Sn 1024
#define Hn 12
#define Dn 768
#define En 64          // head dim
#define Mn (Bn * Sn)   // 8192 rows

typedef unsigned short ushort_t;
typedef __attribute__((ext_vector_type(4))) float f32x4;
typedef __bf16 bf16x8 __attribute__((ext_vector_type(8)));

// RNE f32 -> bf16 (inputs finite; NaN not handled)
__device__ __forceinline__ ushort_t bf_hi(float f) {
    unsigned int u = __float_as_uint(f);
    return (ushort_t)((u + 0x7FFF + ((u >> 16) & 1)) >> 16);
}
__device__ __forceinline__ float bf_f(ushort_t s) {
    return __uint_as_float(((unsigned int)s) << 16);
}

// global -> LDS direct copy, 16B per lane
#define GLL16(gp, lp)                                                        \
    __builtin_amdgcn_global_load_lds(                                        \
        (__attribute__((address_space(1))) void*)(gp),                       \
        (__attribute__((address_space(3))) void*)(lp), 16, 0, 0)

// ---------------------------------------------------------------------------
// Pre-pass A: split x [8192][768] f32 into hi/lo bf16 (same layout).
// ---------------------------------------------------------------------------
__global__ __launch_bounds__(256) void split_x_kernel(
    const float4* __restrict__ x4,
    ushort_t* __restrict__ xh, ushort_t* __restrict__ xl)
{
    int idx = blockIdx.x * 256 + threadIdx.x;   // 0 .. 1572863
    float4 f = x4[idx];
    ushort_t h0 = bf_hi(f.x), h1 = bf_hi(f.y), h2 = bf_hi(f.z), h3 = bf_hi(f.w);
    ushort_t l0 = bf_hi(f.x - bf_f(h0));
    ushort_t l1 = bf_hi(f.y - bf_f(h1));
    ushort_t l2 = bf_hi(f.z - bf_f(h2));
    ushort_t l3 = bf_hi(f.w - bf_f(h3));
    ushort4 hv = make_ushort4(h0, h1, h2, h3);
    ushort4 lv = make_ushort4(l0, l1, l2, l3);
    *(ushort4*)&xh[(size_t)idx * 4] = hv;
    *(ushort4*)&xl[(size_t)idx * 4] = lv;
}

// ---------------------------------------------------------------------------
// Pre-pass B: split + transpose W[h][d][e] -> Wt[w][h][e][d] hi/lo bf16.
// One 64d x 64e tile per block.
// ---------------------------------------------------------------------------
__global__ __launch_bounds__(256) void split_w_kernel(
    const float* __restrict__ Wq, const float* __restrict__ Wk,
    const float* __restrict__ Wv,
    ushort_t* __restrict__ wth, ushort_t* __restrict__ wtl)
{
    const int dt = blockIdx.x;   // 0..11 (64-wide d tile)
    const int h  = blockIdx.y;   // 0..11
    const int w  = blockIdx.z;   // 0..2
    const float* Wp = (w == 0) ? Wq : (w == 1) ? Wk : Wv;

    __shared__ float Ws[64][65];
    const int tid = threadIdx.x;

    #pragma unroll
    for (int t = 0; t < 16; ++t) {
        int idx = tid + t * 256;          // 0..4095
        int d = idx >> 6, e = idx & 63;
        Ws[d][e] = Wp[((size_t)h * Dn + dt * 64 + d) * En + e];
    }
    __syncthreads();

    ushort_t* oh = wth + ((size_t)w * Hn + h) * En * Dn;
    ushort_t* ol = wtl + ((size_t)w * Hn + h) * En * Dn;
    #pragma unroll
    for (int t = 0; t < 16; ++t) {
        int idx = tid + t * 256;
        int e = idx >> 6, dd = idx & 63;
        float f = Ws[dd][e];
        ushort_t hi = bf_hi(f);
        oh[(size_t)e * Dn + dt * 64 + dd] = hi;
        ol[(size_t)e * Dn + dt * 64 + dd] = bf_hi(f - bf_f(hi));
    }
}

// ---------------------------------------------------------------------------
// Kernel 1: QKV projection via bf16x3 MFMA.
// Tile 128(m) x 64(e), BK=64.  4 waves: 2x2, each wave 64x32 (4x2 frags).
// A = x (hi/lo bf16, [m][k]); B = Wt (hi/lo bf16, [e][k]); fp32 accum + out.
// ---------------------------------------------------------------------------
__global__ __launch_bounds__(256) void qkv_mfma_kernel(
    const ushort_t* __restrict__ xh, const ushort_t* __restrict__ xl,
    const ushort_t* __restrict__ wth, const ushort_t* __restrict__ wtl,
    const float* __restrict__ bq, const float* __restrict__ bk,
    const float* __restrict__ bv,
    float* __restrict__ Qo, float* __restrict__ Ko, float* __restrict__ Vo)
{
    const int mt = blockIdx.x;   // 0..63
    const int h  = blockIdx.y;   // 0..11
    const int w  = blockIdx.z;   // 0..2
    const float* bp = (w == 0) ? bq : (w == 1) ? bk : bv;
    float*      Op  = (w == 0) ? Qo : (w == 1) ? Ko : Vo;
    const ushort_t* Wh = wth + ((size_t)w * Hn + h) * En * Dn;   // [64][768]
    const ushort_t* Wl = wtl + ((size_t)w * Hn + h) * En * Dn;

    __shared__ __align__(16) ushort_t Ah[128 * 64];
    __shared__ __align__(16) ushort_t Al[128 * 64];
    __shared__ __align__(16) ushort_t Bh[64 * 64];
    __shared__ __align__(16) ushort_t Bl[64 * 64];

    const int tid  = threadIdx.x;
    const int lane = tid & 63;
    const int wid  = tid >> 6;
    const int wm   = wid >> 1;   // 0..1 : 64-row half
    const int wn   = wid & 1;    // 0..1 : 32-col half
    const int m0   = mt * 128;

    f32x4 acc[4][2] = {};

    for (int k0 = 0; k0 < Dn; k0 += 64) {
        if (k0) __syncthreads();
        // stage A hi/lo: 1024 16B chunks each (row = c>>3, slot = c&7)
        #pragma unroll
        for (int t = 0; t < 4; ++t) {
            int c = tid + t * 256;
            int r = c >> 3, sl = c & 7;
            size_t go = (size_t)(m0 + r) * Dn + k0 + sl * 8;
            GLL16(xh + go, &Ah[c * 8]);
            GLL16(xl + go, &Al[c * 8]);
        }
        // stage B hi/lo: 512 chunks each (row e = c>>3)
        #pragma unroll
        for (int t = 0; t < 2; ++t) {
            int c = tid + t * 256;
            int r = c >> 3, sl = c & 7;
            size_t go = (size_t)r * Dn + k0 + sl * 8;
            GLL16(Wh + go, &Bh[c * 8]);
            GLL16(Wl + go, &Bl[c * 8]);
        }
        __syncthreads();

        #pragma unroll
        for (int ks = 0; ks < 2; ++ks) {
            const int kb = ks * 32 + (lane >> 4) * 8;
            bf16x8 a_h[4], a_l[4], b_h[2], b_l[2];
            #pragma unroll
            for (int i = 0; i < 4; ++i) {
                int row = wm * 64 + i * 16 + (lane & 15);
                a_h[i] = *(const bf16x8*)&Ah[row * 64 + kb];
                a_l[i] = *(const bf16x8*)&Al[row * 64 + kb];
            }
            #pragma unroll
            for (int j = 0; j < 2; ++j) {
                int col = wn * 32 + j * 16 + (lane & 15);
                b_h[j] = *(const bf16x8*)&Bh[col * 64 + kb];
                b_l[j] = *(const bf16x8*)&Bl[col * 64 + kb];
            }
            #pragma unroll
            for (int i = 0; i < 4; ++i)
                #pragma unroll
                for (int j = 0; j < 2; ++j) {
                    acc[i][j] = __builtin_amdgcn_mfma_f32_16x16x32_bf16(
                        a_h[i], b_h[j], acc[i][j], 0, 0, 0);
                    acc[i][j] = __builtin_amdgcn_mfma_f32_16x16x32_bf16(
                        a_l[i], b_h[j], acc[i][j], 0, 0, 0);
                    acc[i][j] = __builtin_amdgcn_mfma_f32_16x16x32_bf16(
                        a_h[i], b_l[j], acc[i][j], 0, 0, 0);
                }
        }
    }

    // epilogue: C/D layout col=lane&15, row=(lane>>4)*4+r  [m89-verified]
    #pragma unroll
    for (int j = 0; j < 2; ++j) {
        int col = wn * 32 + j * 16 + (lane & 15);
        float bb = bp[h * En + col];
        #pragma unroll
        for (int i = 0; i < 4; ++i) {
            #pragma unroll
            for (int r = 0; r < 4; ++r) {
                int m = m0 + wm * 64 + i * 16 + (lane >> 4) * 4 + r;
                int bidx = m >> 10, s = m & 1023;
                Op[(size_t)((bidx * Hn + h) * Sn + s) * En + col] =
                    acc[i][j][r] + bb;
            }
        }
    }
}

// ---------------------------------------------------------------------------
// Kernel 2: raw scores = Q @ K^T * 0.125 per (b,h).  (unchanged, fp32 VALU)
// ---------------------------------------------------------------------------
__global__ __launch_bounds__(256) void scores_kernel(
    const float* __restrict__ Q, const float* __restrict__ K,
    float* __restrict__ Sc)
{
    const int nt = blockIdx.x;   // key tile 0..15
    const int mt = blockIdx.y;   // query tile 0..15
    const int bh = blockIdx.z;   // 0..95

    __shared__ float As[64][68];   // [k][m] q
    __shared__ float Bs[64][68];   // [k][n] keys

    const int tid = threadIdx.x;
    const int tr = tid >> 4, tc = tid & 15;
    const float* Qp = Q + (size_t)bh * Sn * En;
    const float* Kp = K + (size_t)bh * Sn * En;
    const int m0 = mt * 64, n0 = nt * 64;

    #pragma unroll
    for (int t = 0; t < 16; ++t) {
        int idx = tid + t * 256;         // 0..4095
        int i = idx >> 6, k = idx & 63;
        As[k][i] = Qp[(size_t)(m0 + i) * En + k];
        Bs[k][i] = Kp[(size_t)(n0 + i) * En + k];
    }
    __syncthreads();

    float acc[4][4] = {};
    #pragma unroll 8
    for (int k = 0; k < 64; ++k) {
        float4 a = *(const float4*)&As[k][tr * 4];
        float4 b = *(const float4*)&Bs[k][tc * 4];
        float av[4] = {a.x, a.y, a.z, a.w};
        float bv2[4] = {b.x, b.y, b.z, b.w};
        #pragma unroll
        for (int i = 0; i < 4; ++i)
            #pragma unroll
            for (int j = 0; j < 4; ++j) acc[i][j] += av[i] * bv2[j];
    }

    #pragma unroll
    for (int i = 0; i < 4; ++i) {
        int row = m0 + tr * 4 + i;
        float4 o;
        o.x = acc[i][0] * 0.125f;  o.y = acc[i][1] * 0.125f;
        o.z = acc[i][2] * 0.125f;  o.w = acc[i][3] * 0.125f;
        *(float4*)&Sc[(size_t)(bh * Sn + row) * Sn + n0 + tc * 4] = o;
    }
}

// ---------------------------------------------------------------------------
// Kernel 3: softmax + probs write + P @ V.  (unchanged, fp32 VALU)
// ---------------------------------------------------------------------------
__global__ __launch_bounds__(256) void softmax_pv_kernel(
    float* __restrict__ Sc,            // in: raw scores, out: final probs
    const float* __restrict__ V,
    float* __restrict__ CTX)           // [B,S,H*En]
{
    const int mt = blockIdx.x;   // 0..15 row block
    const int bh = blockIdx.y;   // 0..95
    const int bb = bh / Hn, h = bh % Hn;

    __shared__ float Ps[64][68];   // [key][row]  normalized p tile
    __shared__ float Vs[64][68];   // [key][e]
    __shared__ float red[64][4];
    __shared__ float invl[64];

    const int tid = threadIdx.x;
    float* ScRow = Sc + (size_t)(bh * Sn + mt * 64) * Sn;
    const float* Vp = V + (size_t)bh * Sn * En;

    // ---- phase A: per-row sum of exp(score) ----
    {
        const int r = tid >> 2, t4 = tid & 3;
        const float* src = ScRow + (size_t)r * Sn;
        float l = 0.f;
        for (int k = 0; k < 64; ++k) {
            float4 s4 = *(const float4*)&src[(t4 + 4 * k) * 4];
            l += __expf(s4.x) + __expf(s4.y) + __expf(s4.z) + __expf(s4.w);
        }
        red[r][t4] = l;
        __syncthreads();
        if (t4 == 0)
            invl[r] = 1.f / (red[r][0] + red[r][1] + red[r][2] + red[r][3]);
        __syncthreads();
    }

    // ---- phase B: normalize + write probs + PV GEMM ----
    const int tr = tid >> 4, tc = tid & 15;
    float acc[4][4] = {};

    for (int kt = 0; kt < 16; ++kt) {
        if (kt) __syncthreads();   // protect Ps/Vs against previous readers
        #pragma unroll
        for (int t = 0; t < 16; ++t) {
            int idx = tid + t * 256;       // 0..4095
            int mm = idx >> 6, kk = idx & 63;
            size_t off = (size_t)mm * Sn + kt * 64 + kk;
            float p = __expf(ScRow[off]) * invl[mm];
            ScRow[off] = p;
            Ps[kk][mm] = p;
            Vs[mm][kk] = Vp[(size_t)(kt * 64 + mm) * En + kk];
        }
        __syncthreads();
        #pragma unroll 8
        for (int k = 0; k < 64; ++k) {
            float4 a = *(const float4*)&Ps[k][tr * 4];
            float4 b = *(const float4*)&Vs[k][tc * 4];
            float av[4] = {a.x, a.y, a.z, a.w};
            float bv2[4] = {b.x, b.y, b.z, b.w};
            #pragma unroll
            for (int i = 0; i < 4; ++i)
                #pragma unroll
                for (int j = 0; j < 4; ++j) acc[i][j] += av[i] * bv2[j];
        }
    }

    #pragma unroll
    for (int i = 0; i < 4; ++i) {
        int s = mt * 64 + tr * 4 + i;
        float4 o;
        o.x = acc[i][0];  o.y = acc[i][1];  o.z = acc[i][2];  o.w = acc[i][3];
        *(float4*)&CTX[(size_t)(bb * Sn + s) * Dn + h * En + tc * 4] = o;
    }
}

// ---------------------------------------------------------------------------
// Kernel 4: out = CTX @ Wo^T + bo.  (unchanged, fp32 VALU)
// ---------------------------------------------------------------------------
__global__ __launch_bounds__(256) void out_kernel(
    const float* __restrict__ CTX, const float* __restrict__ Wo,
    const float* __restrict__ bo, float* __restrict__ out)
{
    const int mt = blockIdx.x;   // 0..127
    const int nt = blockIdx.y;   // 0..11

    __shared__ float As[32][68];   // [k][m]
    __shared__ float Bs[32][68];   // [k][n]

    const int tid = threadIdx.x;
    const int tr = tid >> 4, tc = tid & 15;
    const int m0 = mt * 64, n0 = nt * 64;

    float acc[4][4] = {};

    for (int k0 = 0; k0 < Dn; k0 += 32) {
        #pragma unroll
        for (int t = 0; t < 8; ++t) {
            int idx = tid + t * 256;
            int i = idx >> 5, kk = idx & 31;
            As[kk][i] = CTX[(size_t)(m0 + i) * Dn + k0 + kk];
            Bs[kk][i] = Wo[(size_t)(n0 + i) * Dn + k0 + kk];
        }
        __syncthreads();
        #pragma unroll 8
        for (int kk = 0; kk < 32; ++kk) {
            float4 a = *(const float4*)&As[kk][tr * 4];
            float4 b = *(const float4*)&Bs[kk][tc * 4];
            float av[4] = {a.x, a.y, a.z, a.w};
            float bv2[4] = {b.x, b.y, b.z, b.w};
            #pragma unroll
            for (int i = 0; i < 4; ++i)
                #pragma unroll
                for (int j = 0; j < 4; ++j) acc[i][j] += av[i] * bv2[j];
        }
        __syncthreads();
    }

    const float4 bb = *(const float4*)&bo[n0 + tc * 4];
    #pragma unroll
    for (int i = 0; i < 4; ++i) {
        int m = m0 + tr * 4 + i;
        float4 o;
        o.x = acc[i][0] + bb.x;  o.y = acc[i][1] + bb.y;
        o.z = acc[i][2] + bb.z;  o.w = acc[i][3] + bb.w;
        *(float4*)&out[(size_t)m * Dn + n0 + tc * 4] = o;
    }
}

// ---------------------------------------------------------------------------
extern "C" void kernel_launch(void* const* d_in, const int* in_sizes, int n_in,
                              void* d_out, int out_size, void* d_ws, size_t ws_size,
                              hipStream_t stream)
{
    const float* x  = (const float*)d_in[0];
    const float* Wq = (const float*)d_in[1];
    const float* bq = (const float*)d_in[2];
    const float* Wk = (const float*)d_in[3];
    const float* bk = (const float*)d_in[4];
    const float* Wv = (const float*)d_in[5];
    const float* bv = (const float*)d_in[6];
    const float* Wo = (const float*)d_in[7];
    const float* bo = (const float*)d_in[8];

    float* out = (float*)d_out;
    const size_t QSZ = (size_t)Bn * Hn * Sn * En;      // 6,291,456 floats
    float* probs = out + (size_t)Bn * Sn * Dn;         // probs region of d_out

    float* ws  = (float*)d_ws;
    float* Q   = ws;
    float* K   = ws + QSZ;
    float* V   = ws + 2 * QSZ;
    float* CTX = ws + 3 * QSZ;

    // Scratch aliases (all dead by the time their later writers run):
    //  - x hi/lo bf16 live in the CTX region (CTX written by kernel 3, after qkv)
    //  - Wt hi/lo bf16 live at the head of probs (overwritten by scores_kernel)
    ushort_t* xh  = (ushort_t*)CTX;                       // 6.29M ushorts
    ushort_t* xl  = xh + (size_t)Mn * Dn;                 // 6.29M ushorts
    ushort_t* wth = (ushort_t*)probs;                     // 3*12*64*768 each
    ushort_t* wtl = wth + (size_t)3 * Hn * En * Dn;

    split_x_kernel<<<dim3(Mn * Dn / 4 / 256), 256, 0, stream>>>(
        (const float4*)x, xh, xl);

    split_w_kernel<<<dim3(Dn / 64, Hn, 3), 256, 0, stream>>>(
        Wq, Wk, Wv, wth, wtl);

    qkv_mfma_kernel<<<dim3(Mn / 128, Hn, 3), 256, 0, stream>>>(
        xh, xl, wth, wtl, bq, bk, bv, Q, K, V);

    scores_kernel<<<dim3(Sn / 64, Sn / 64, Bn * Hn), 256, 0, stream>>>(
        Q, K, probs);

    softmax_pv_kernel<<<dim3(Sn / 64, Bn * Hn), 256, 0, stream>>>(
        probs, V, CTX);

    out_kernel<<<dim3(Mn / 64, Dn / 64), 256, 0, stream>>>(
        CTX, Wo, bo, out);
}

// Round 3
// 742.859 us; speedup vs baseline: 2.6255x; 1.9163x over previous
//
#include <hip/hip_runtime.h>
#include <cstddef>

// Problem constants
#define Bn 8
#define Sn 1024
#define Hn 12
#define Dn 768
#define En 64          // head dim
#define Mn (Bn * Sn)   // 8192 rows

typedef unsigned short ushort_t;
typedef __attribute__((ext_vector_type(4))) float f32x4;
typedef __bf16 bf16x8 __attribute__((ext_vector_type(8)));

#define MFMA(a, b, c) __builtin_amdgcn_mfma_f32_16x16x32_bf16(a, b, c, 0, 0, 0)

// RNE f32 -> bf16 (inputs finite; NaN not handled)
__device__ __forceinline__ ushort_t bf_hi(float f) {
    unsigned int u = __float_as_uint(f);
    return (ushort_t)((u + 0x7FFF + ((u >> 16) & 1)) >> 16);
}
__device__ __forceinline__ float bf_f(ushort_t s) {
    return __uint_as_float(((unsigned int)s) << 16);
}

// global -> LDS direct copy, 16B per lane
#define GLL16(gp, lp)                                                        \
    __builtin_amdgcn_global_load_lds(                                        \
        (__attribute__((address_space(1))) void*)(gp),                       \
        (__attribute__((address_space(3))) void*)(lp), 16, 0, 0)

// ---------------------------------------------------------------------------
// Pre-pass A: split x [8192][768] f32 into hi/lo bf16 (same layout).
// ---------------------------------------------------------------------------
__global__ __launch_bounds__(256) void split_x_kernel(
    const float4* __restrict__ x4,
    ushort_t* __restrict__ xh, ushort_t* __restrict__ xl)
{
    int idx = blockIdx.x * 256 + threadIdx.x;   // 0 .. 1572863
    float4 f = x4[idx];
    ushort_t h0 = bf_hi(f.x), h1 = bf_hi(f.y), h2 = bf_hi(f.z), h3 = bf_hi(f.w);
    ushort_t l0 = bf_hi(f.x - bf_f(h0));
    ushort_t l1 = bf_hi(f.y - bf_f(h1));
    ushort_t l2 = bf_hi(f.z - bf_f(h2));
    ushort_t l3 = bf_hi(f.w - bf_f(h3));
    *(ushort4*)&xh[(size_t)idx * 4] = make_ushort4(h0, h1, h2, h3);
    *(ushort4*)&xl[(size_t)idx * 4] = make_ushort4(l0, l1, l2, l3);
}

// ---------------------------------------------------------------------------
// Pre-pass B: split + transpose W[h][d][e] -> Wt[w][h][e][d] hi/lo bf16.
// ---------------------------------------------------------------------------
__global__ __launch_bounds__(256) void split_w_kernel(
    const float* __restrict__ Wq, const float* __restrict__ Wk,
    const float* __restrict__ Wv,
    ushort_t* __restrict__ wth, ushort_t* __restrict__ wtl)
{
    const int dt = blockIdx.x;   // 0..11 (64-wide d tile)
    const int h  = blockIdx.y;   // 0..11
    const int w  = blockIdx.z;   // 0..2
    const float* Wp = (w == 0) ? Wq : (w == 1) ? Wk : Wv;

    __shared__ float Ws[64][65];
    const int tid = threadIdx.x;

    #pragma unroll
    for (int t = 0; t < 16; ++t) {
        int idx = tid + t * 256;          // 0..4095
        int d = idx >> 6, e = idx & 63;
        Ws[d][e] = Wp[((size_t)h * Dn + dt * 64 + d) * En + e];
    }
    __syncthreads();

    ushort_t* oh = wth + ((size_t)w * Hn + h) * En * Dn;
    ushort_t* ol = wtl + ((size_t)w * Hn + h) * En * Dn;
    #pragma unroll
    for (int t = 0; t < 16; ++t) {
        int idx = tid + t * 256;
        int e = idx >> 6, dd = idx & 63;
        float f = Ws[dd][e];
        ushort_t hi = bf_hi(f);
        oh[(size_t)e * Dn + dt * 64 + dd] = hi;
        ol[(size_t)e * Dn + dt * 64 + dd] = bf_hi(f - bf_f(hi));
    }
}

// ---------------------------------------------------------------------------
// Kernel 1: QKV projection via bf16x3 MFMA.  Outputs bf16 hi/lo directly:
//   Q,K: [bh][s][e];  V transposed: [bh][e][s]  (PV B-operand layout).
// Tile 128(m) x 64(e), BK=64.  LDS XOR-swizzled (^((row&7)<<3) ushort idx).
// ---------------------------------------------------------------------------
__global__ __launch_bounds__(256) void qkv_mfma_kernel(
    const ushort_t* __restrict__ xh, const ushort_t* __restrict__ xl,
    const ushort_t* __restrict__ wth, const ushort_t* __restrict__ wtl,
    const float* __restrict__ bq, const float* __restrict__ bk,
    const float* __restrict__ bv,
    ushort_t* __restrict__ Qh, ushort_t* __restrict__ Ql,
    ushort_t* __restrict__ Kh, ushort_t* __restrict__ Kl,
    ushort_t* __restrict__ Vth, ushort_t* __restrict__ Vtl)
{
    const int mt = blockIdx.x;   // 0..63
    const int h  = blockIdx.y;   // 0..11
    const int w  = blockIdx.z;   // 0..2
    const float* bp = (w == 0) ? bq : (w == 1) ? bk : bv;
    ushort_t* OH = (w == 0) ? Qh : (w == 1) ? Kh : Vth;
    ushort_t* OL = (w == 0) ? Ql : (w == 1) ? Kl : Vtl;
    const ushort_t* Wh = wth + ((size_t)w * Hn + h) * En * Dn;   // [64][768]
    const ushort_t* Wl = wtl + ((size_t)w * Hn + h) * En * Dn;

    __shared__ __align__(16) ushort_t Ah[128 * 64];
    __shared__ __align__(16) ushort_t Al[128 * 64];
    __shared__ __align__(16) ushort_t Bh[64 * 64];
    __shared__ __align__(16) ushort_t Bl[64 * 64];

    const int tid  = threadIdx.x;
    const int lane = tid & 63;
    const int lr   = lane & 15, lg = lane >> 4;
    const int wid  = tid >> 6;
    const int wm   = wid >> 1;   // 0..1 : 64-row half
    const int wn   = wid & 1;    // 0..1 : 32-col half
    const int m0   = mt * 128;

    f32x4 acc[4][2] = {};

    for (int k0 = 0; k0 < Dn; k0 += 64) {
        if (k0) __syncthreads();
        #pragma unroll
        for (int t = 0; t < 4; ++t) {        // A hi/lo: 1024 chunks each
            int c = tid + t * 256;
            int r = c >> 3, sl = (c & 7) ^ (r & 7);
            size_t go = (size_t)(m0 + r) * Dn + k0 + sl * 8;
            GLL16(xh + go, &Ah[c * 8]);
            GLL16(xl + go, &Al[c * 8]);
        }
        #pragma unroll
        for (int t = 0; t < 2; ++t) {        // B hi/lo: 512 chunks each
            int c = tid + t * 256;
            int r = c >> 3, sl = (c & 7) ^ (r & 7);
            size_t go = (size_t)r * Dn + k0 + sl * 8;
            GLL16(Wh + go, &Bh[c * 8]);
            GLL16(Wl + go, &Bl[c * 8]);
        }
        __syncthreads();

        #pragma unroll
        for (int ks = 0; ks < 2; ++ks) {
            const int kb = ks * 32 + lg * 8;
            bf16x8 a_h[4], a_l[4], b_h[2], b_l[2];
            #pragma unroll
            for (int i = 0; i < 4; ++i) {
                int row = wm * 64 + i * 16 + lr;
                int ai = (row * 64 + kb) ^ ((row & 7) << 3);
                a_h[i] = *(const bf16x8*)&Ah[ai];
                a_l[i] = *(const bf16x8*)&Al[ai];
            }
            #pragma unroll
            for (int j = 0; j < 2; ++j) {
                int col = wn * 32 + j * 16 + lr;
                int bi = (col * 64 + kb) ^ ((col & 7) << 3);
                b_h[j] = *(const bf16x8*)&Bh[bi];
                b_l[j] = *(const bf16x8*)&Bl[bi];
            }
            #pragma unroll
            for (int i = 0; i < 4; ++i)
                #pragma unroll
                for (int j = 0; j < 2; ++j) {
                    acc[i][j] = MFMA(a_h[i], b_h[j], acc[i][j]);
                    acc[i][j] = MFMA(a_l[i], b_h[j], acc[i][j]);
                    acc[i][j] = MFMA(a_h[i], b_l[j], acc[i][j]);
                }
        }
    }

    // epilogue: C/D layout col=lane&15, row=(lane>>4)*4+r
    #pragma unroll
    for (int j = 0; j < 2; ++j) {
        int col = wn * 32 + j * 16 + lr;
        float bb = bp[h * En + col];
        #pragma unroll
        for (int i = 0; i < 4; ++i) {
            #pragma unroll
            for (int r = 0; r < 4; ++r) {
                int m = m0 + wm * 64 + i * 16 + lg * 4 + r;
                int bidx = m >> 10, s = m & 1023;
                float v = acc[i][j][r] + bb;
                ushort_t vh = bf_hi(v);
                ushort_t vl = bf_hi(v - bf_f(vh));
                size_t off;
                if (w < 2)   // [bh][s][e]
                    off = (size_t)((bidx * Hn + h) * Sn + s) * En + col;
                else         // V transposed: [bh][e][s]
                    off = (size_t)((bidx * Hn + h) * En + col) * Sn + s;
                OH[off] = vh;
                OL[off] = vl;
            }
        }
    }
}

// ---------------------------------------------------------------------------
// Kernel 2: fused scores+softmax+probs+PV (flash-style, 2-pass recompute).
// Block: one (bh, 64-q-row tile); 4 waves x 16 q-rows each.
// ---------------------------------------------------------------------------
__global__ __launch_bounds__(256) void attn_kernel(
    const ushort_t* __restrict__ Qh, const ushort_t* __restrict__ Ql,
    const ushort_t* __restrict__ Kh_g, const ushort_t* __restrict__ Kl_g,
    const ushort_t* __restrict__ Vth_g, const ushort_t* __restrict__ Vtl_g,
    float* __restrict__ Pr,
    ushort_t* __restrict__ CTXh, ushort_t* __restrict__ CTXl)
{
    const int qt = blockIdx.x;    // 0..15
    const int bh = blockIdx.y;    // 0..95
    const int bb = bh / Hn, h = bh % Hn;

    __shared__ __align__(16) ushort_t Ks[2][64 * 64];  // hi,lo  [key][e] swz
    __shared__ __align__(16) ushort_t Vs[2][64 * 64];  // hi,lo  [e][key] swz
    __shared__ __align__(16) ushort_t Ps[2][64 * 64];  // hi,lo  [q][key] swz

    const int tid = threadIdx.x, lane = tid & 63, w = tid >> 6;
    const int lr = lane & 15, lg = lane >> 4;

    const ushort_t* KH  = Kh_g  + (size_t)bh * Sn * En;   // [s][e]
    const ushort_t* KL  = Kl_g  + (size_t)bh * Sn * En;
    const ushort_t* VTH = Vth_g + (size_t)bh * En * Sn;   // [e][s]
    const ushort_t* VTL = Vtl_g + (size_t)bh * En * Sn;

    // Q fragments held in registers: row q = qt*64 + w*16 + lr
    bf16x8 qfh[2], qfl[2];
    {
        size_t off = ((size_t)bh * Sn + qt * 64 + w * 16 + lr) * En + lg * 8;
        qfh[0] = *(const bf16x8*)&Qh[off];
        qfh[1] = *(const bf16x8*)&Qh[off + 32];
        qfl[0] = *(const bf16x8*)&Ql[off];
        qfl[1] = *(const bf16x8*)&Ql[off + 32];
    }

    float rs[4] = {0.f, 0.f, 0.f, 0.f};

    // ---- pass 1: row sums of exp(S/8) ----
    for (int kt = 0; kt < 16; ++kt) {
        __syncthreads();
        #pragma unroll
        for (int t = 0; t < 2; ++t) {
            int c = tid + t * 256;
            int r = c >> 3, sl = (c & 7) ^ (r & 7);
            size_t go = (size_t)(kt * 64 + r) * En + sl * 8;
            GLL16(KH + go, &Ks[0][c * 8]);
            GLL16(KL + go, &Ks[1][c * 8]);
        }
        __syncthreads();

        f32x4 sacc[4] = {};
        #pragma unroll
        for (int ks = 0; ks < 2; ++ks) {
            #pragma unroll
            for (int j = 0; j < 4; ++j) {
                int key = j * 16 + lr;
                int bi = (key * 64 + ks * 32 + lg * 8) ^ ((key & 7) << 3);
                bf16x8 kh = *(const bf16x8*)&Ks[0][bi];
                bf16x8 kl = *(const bf16x8*)&Ks[1][bi];
                sacc[j] = MFMA(qfh[ks], kh, sacc[j]);
                sacc[j] = MFMA(qfl[ks], kh, sacc[j]);
                sacc[j] = MFMA(qfh[ks], kl, sacc[j]);
            }
        }
        #pragma unroll
        for (int j = 0; j < 4; ++j)
            #pragma unroll
            for (int r = 0; r < 4; ++r)
                rs[r] += __expf(0.125f * sacc[j][r]);
    }
    // reduce over the 16 column-holder lanes; rs becomes 1/rowsum
    #pragma unroll
    for (int r = 0; r < 4; ++r) {
        float v = rs[r];
        v += __shfl_xor(v, 1);
        v += __shfl_xor(v, 2);
        v += __shfl_xor(v, 4);
        v += __shfl_xor(v, 8);
        rs[r] = 1.f / v;
    }

    // ---- pass 2: recompute, write probs, PV ----
    f32x4 cacc[4] = {};
    float* PrRow = Pr + ((size_t)bh * Sn + qt * 64) * Sn;

    for (int kt = 0; kt < 16; ++kt) {
        __syncthreads();
        #pragma unroll
        for (int t = 0; t < 2; ++t) {
            int c = tid + t * 256;
            int r = c >> 3, sl = (c & 7) ^ (r & 7);
            size_t gk = (size_t)(kt * 64 + r) * En + sl * 8;
            GLL16(KH + gk, &Ks[0][c * 8]);
            GLL16(KL + gk, &Ks[1][c * 8]);
            size_t gv = (size_t)r * Sn + kt * 64 + sl * 8;
            GLL16(VTH + gv, &Vs[0][c * 8]);
            GLL16(VTL + gv, &Vs[1][c * 8]);
        }
        __syncthreads();

        f32x4 sacc[4] = {};
        #pragma unroll
        for (int ks = 0; ks < 2; ++ks) {
            #pragma unroll
            for (int j = 0; j < 4; ++j) {
                int key = j * 16 + lr;
                int bi = (key * 64 + ks * 32 + lg * 8) ^ ((key & 7) << 3);
                bf16x8 kh = *(const bf16x8*)&Ks[0][bi];
                bf16x8 kl = *(const bf16x8*)&Ks[1][bi];
                sacc[j] = MFMA(qfh[ks], kh, sacc[j]);
                sacc[j] = MFMA(qfl[ks], kh, sacc[j]);
                sacc[j] = MFMA(qfh[ks], kl, sacc[j]);
            }
        }

        // normalize, write probs (f32), stash P hi/lo in swizzled LDS
        #pragma unroll
        for (int j = 0; j < 4; ++j) {
            int key = j * 16 + lr;
            #pragma unroll
            for (int r = 0; r < 4; ++r) {
                int q = w * 16 + lg * 4 + r;          // block-local q row
                float p = __expf(0.125f * sacc[j][r]) * rs[r];
                PrRow[(size_t)q * Sn + kt * 64 + key] = p;
                ushort_t ph = bf_hi(p);
                int pi = (q * 64 + key) ^ ((q & 7) << 3);
                Ps[0][pi] = ph;
                Ps[1][pi] = bf_hi(p - bf_f(ph));
            }
        }

        // PV: A = P rows of this wave (own LDS slice), B = Vt
        #pragma unroll
        for (int ks = 0; ks < 2; ++ks) {
            int qa = w * 16 + lr;
            int ai = (qa * 64 + ks * 32 + lg * 8) ^ ((qa & 7) << 3);
            bf16x8 pah = *(const bf16x8*)&Ps[0][ai];
            bf16x8 pal = *(const bf16x8*)&Ps[1][ai];
            #pragma unroll
            for (int j = 0; j < 4; ++j) {
                int er = j * 16 + lr;
                int bi = (er * 64 + ks * 32 + lg * 8) ^ ((er & 7) << 3);
                bf16x8 vh = *(const bf16x8*)&Vs[0][bi];
                bf16x8 vl = *(const bf16x8*)&Vs[1][bi];
                cacc[j] = MFMA(pah, vh, cacc[j]);
                cacc[j] = MFMA(pal, vh, cacc[j]);
                cacc[j] = MFMA(pah, vl, cacc[j]);
            }
        }
    }

    // epilogue: CTX bf16 hi/lo, [b][s][h*64+e]
    #pragma unroll
    for (int j = 0; j < 4; ++j) {
        #pragma unroll
        for (int r = 0; r < 4; ++r) {
            int s = qt * 64 + w * 16 + lg * 4 + r;
            int e = j * 16 + lr;
            float v = cacc[j][r];
            ushort_t vh = bf_hi(v);
            size_t off = ((size_t)bb * Sn + s) * Dn + h * En + e;
            CTXh[off] = vh;
            CTXl[off] = bf_hi(v - bf_f(vh));
        }
    }
}

// ---------------------------------------------------------------------------
// Kernel 3: out = CTX @ Wo^T + bo via bf16x3 MFMA.
// ---------------------------------------------------------------------------
__global__ __launch_bounds__(256) void out_mfma_kernel(
    const ushort_t* __restrict__ CTXh, const ushort_t* __restrict__ CTXl,
    const float* __restrict__ Wo, const float* __restrict__ bo,
    float* __restrict__ out)
{
    const int mt = blockIdx.x;   // 0..63
    const int nt = blockIdx.y;   // 0..11

    __shared__ __align__(16) ushort_t Ah[128 * 64];
    __shared__ __align__(16) ushort_t Al[128 * 64];
    __shared__ __align__(16) ushort_t Bh[64 * 64];
    __shared__ __align__(16) ushort_t Bl[64 * 64];

    const int tid  = threadIdx.x;
    const int lane = tid & 63;
    const int lr   = lane & 15, lg = lane >> 4;
    const int wid  = tid >> 6;
    const int wm   = wid >> 1, wn = wid & 1;
    const int m0   = mt * 128, n0 = nt * 64;

    f32x4 acc[4][2] = {};

    for (int k0 = 0; k0 < Dn; k0 += 64) {
        if (k0) __syncthreads();
        #pragma unroll
        for (int t = 0; t < 4; ++t) {
            int c = tid + t * 256;
            int r = c >> 3, sl = (c & 7) ^ (r & 7);
            size_t go = (size_t)(m0 + r) * Dn + k0 + sl * 8;
            GLL16(CTXh + go, &Ah[c * 8]);
            GLL16(CTXl + go, &Al[c * 8]);
        }
        // B: load Wo f32, split to hi/lo bf16, swizzled LDS write
        #pragma unroll
        for (int t = 0; t < 4; ++t) {
            int idx = tid + t * 256;          // 0..1023 float4-quads
            int n = idx >> 4, f4 = idx & 15;
            float4 f = *(const float4*)&Wo[(size_t)(n0 + n) * Dn + k0 + f4 * 4];
            ushort_t h0 = bf_hi(f.x), h1 = bf_hi(f.y);
            ushort_t h2 = bf_hi(f.z), h3 = bf_hi(f.w);
            unsigned int hi0 = (unsigned)h0 | ((unsigned)h1 << 16);
            unsigned int hi1 = (unsigned)h2 | ((unsigned)h3 << 16);
            unsigned int lo0 = (unsigned)bf_hi(f.x - bf_f(h0)) |
                               ((unsigned)bf_hi(f.y - bf_f(h1)) << 16);
            unsigned int lo1 = (unsigned)bf_hi(f.z - bf_f(h2)) |
                               ((unsigned)bf_hi(f.w - bf_f(h3)) << 16);
            int di = (n * 64 + f4 * 4) ^ ((n & 7) << 3);
            *(uint2*)&Bh[di] = make_uint2(hi0, hi1);
            *(uint2*)&Bl[di] = make_uint2(lo0, lo1);
        }
        __syncthreads();

        #pragma unroll
        for (int ks = 0; ks < 2; ++ks) {
            const int kb = ks * 32 + lg * 8;
            bf16x8 a_h[4], a_l[4], b_h[2], b_l[2];
            #pragma unroll
            for (int i = 0; i < 4; ++i) {
                int row = wm * 64 + i * 16 + lr;
                int ai = (row * 64 + kb) ^ ((row & 7) << 3);
                a_h[i] = *(const bf16x8*)&Ah[ai];
                a_l[i] = *(const bf16x8*)&Al[ai];
            }
            #pragma unroll
            for (int j = 0; j < 2; ++j) {
                int col = wn * 32 + j * 16 + lr;
                int bi = (col * 64 + kb) ^ ((col & 7) << 3);
                b_h[j] = *(const bf16x8*)&Bh[bi];
                b_l[j] = *(const bf16x8*)&Bl[bi];
            }
            #pragma unroll
            for (int i = 0; i < 4; ++i)
                #pragma unroll
                for (int j = 0; j < 2; ++j) {
                    acc[i][j] = MFMA(a_h[i], b_h[j], acc[i][j]);
                    acc[i][j] = MFMA(a_l[i], b_h[j], acc[i][j]);
                    acc[i][j] = MFMA(a_h[i], b_l[j], acc[i][j]);
                }
        }
    }

    #pragma unroll
    for (int j = 0; j < 2; ++j) {
        int col = n0 + wn * 32 + j * 16 + lr;
        float bb = bo[col];
        #pragma unroll
        for (int i = 0; i < 4; ++i)
            #pragma unroll
            for (int r = 0; r < 4; ++r) {
                int m = m0 + wm * 64 + i * 16 + lg * 4 + r;
                out[(size_t)m * Dn + col] = acc[i][j][r] + bb;
            }
    }
}

// ---------------------------------------------------------------------------
extern "C" void kernel_launch(void* const* d_in, const int* in_sizes, int n_in,
                              void* d_out, int out_size, void* d_ws, size_t ws_size,
                              hipStream_t stream)
{
    const float* x  = (const float*)d_in[0];
    const float* Wq = (const float*)d_in[1];
    const float* bq = (const float*)d_in[2];
    const float* Wk = (const float*)d_in[3];
    const float* bk = (const float*)d_in[4];
    const float* Wv = (const float*)d_in[5];
    const float* bv = (const float*)d_in[6];
    const float* Wo = (const float*)d_in[7];
    const float* bo = (const float*)d_in[8];

    float* out = (float*)d_out;
    const size_t QSZ = (size_t)Bn * Hn * Sn * En;      // 6,291,456 elements
    float* probs = out + (size_t)Bn * Sn * Dn;         // probs region of d_out

    // ws layout (ushort arrays, total = old 4*QSZ float footprint):
    ushort_t* u   = (ushort_t*)d_ws;
    ushort_t* Qh  = u;
    ushort_t* Ql  = Qh + QSZ;
    ushort_t* Kh  = Ql + QSZ;
    ushort_t* Kl  = Kh + QSZ;
    ushort_t* Vth = Kl + QSZ;
    ushort_t* Vtl = Vth + QSZ;
    ushort_t* xh  = Vtl + QSZ;          // dead after qkv ...
    ushort_t* xl  = xh + (size_t)Mn * Dn;
    ushort_t* CTXh = xh;                // ... reused as CTX hi/lo
    ushort_t* CTXl = xl;

    // QKV weight splits live at the head of the probs region (dead before
    // attn_kernel overwrites all of probs).
    ushort_t* wth = (ushort_t*)probs;
    ushort_t* wtl = wth + (size_t)3 * Hn * En * Dn;

    split_x_kernel<<<dim3(Mn * Dn / 4 / 256), 256, 0, stream>>>(
        (const float4*)x, xh, xl);

    split_w_kernel<<<dim3(Dn / 64, Hn, 3), 256, 0, stream>>>(
        Wq, Wk, Wv, wth, wtl);

    qkv_mfma_kernel<<<dim3(Mn / 128, Hn, 3), 256, 0, stream>>>(
        xh, xl, wth, wtl, bq, bk, bv, Qh, Ql, Kh, Kl, Vth, Vtl);

    attn_kernel<<<dim3(Sn / 64, Bn * Hn), 256, 0, stream>>>(
        Qh, Ql, Kh, Kl, Vth, Vtl, probs, CTXh, CTXl);

    out_mfma_kernel<<<dim3(Mn / 128, Dn / 64), 256, 0, stream>>>(
        CTXh, CTXl, Wo, bo, out);
}